// Round 7
// baseline (415.805 us; speedup 1.0000x reference)
//
#include <hip/hip_runtime.h>
#include <hip/hip_bf16.h>
#include <cstdint>
#include <cstddef>

typedef __bf16 bf16_t;
typedef __bf16 bf16x8 __attribute__((ext_vector_type(8)));
typedef float f32x4 __attribute__((ext_vector_type(4)));

#define AS1(p) ((const __attribute__((address_space(1))) void*)(p))
#define AS3(p) ((__attribute__((address_space(3))) void*)(p))

struct bf16x4_s { bf16_t x, y, z, w; };

// ---------------- cast f32 -> bf16, x4 vectorized ----------------
__global__ __launch_bounds__(256) void k_cast_bf16(const float4* __restrict__ in,
                                                   bf16x4_s* __restrict__ out, int n4) {
  int i = blockIdx.x * 256 + threadIdx.x;
  if (i < n4) {
    float4 v = in[i];
    bf16x4_s o{(bf16_t)v.x, (bf16_t)v.y, (bf16_t)v.z, (bf16_t)v.w};
    out[i] = o;
  }
}

// -------- masked transpose f32 [K][N] -> bf16 [N][K] (mask = comp[k][n>>3]) --------
__global__ __launch_bounds__(256) void k_transpose(const float* __restrict__ W,
                                                   const int* __restrict__ comp,
                                                   bf16_t* __restrict__ Bt,
                                                   int K, int N, int Pc) {
  __shared__ float tile[64][65];
  const int k0 = blockIdx.x * 64;
  const int n0 = blockIdx.y * 64;
  const int t = threadIdx.x;
  const int c = t & 63;
  const int r0 = t >> 6;
#pragma unroll
  for (int i = 0; i < 16; ++i) {
    int r = r0 + i * 4;
    float v = W[(size_t)(k0 + r) * N + n0 + c];
    v *= (float)comp[(size_t)(k0 + r) * Pc + ((n0 + c) >> 3)];
    tile[r][c] = v;
  }
  __syncthreads();
#pragma unroll
  for (int i = 0; i < 16; ++i) {
    int r = r0 + i * 4;
    Bt[(size_t)(n0 + r) * K + k0 + c] = (bf16_t)tile[c][r];
  }
}

// -------- W23 builder: W23t[n][k] = sum_d2 fc2w[k][p*16+d2]*w3[p*16+d2][n], p=k/8 --------
__global__ __launch_bounds__(256) void k_w23(const float* __restrict__ fc2w,
                                             const float* __restrict__ w3,
                                             const float* __restrict__ b2,
                                             bf16_t* __restrict__ W23t,
                                             float* __restrict__ b23) {
  __shared__ float w3s[128][65];
  const int n0 = blockIdx.x * 64;
  const int pb = blockIdx.y * 8;
  const int tid = threadIdx.x;
  const int c = tid & 63, q = tid >> 6;
#pragma unroll
  for (int i = 0; i < 32; ++i) {
    int rr = i * 4 + q;
    w3s[rr][c] = w3[(size_t)(pb * 16 + rr) * 2048 + n0 + c];
  }
  __syncthreads();
  const int pp = c >> 3;
  const int k1 = pb * 8 + c;
  const int p = pb + pp;
  float f2[16];
  const float4* frp = (const float4*)(fc2w + (size_t)k1 * 8192 + (size_t)p * 16);
#pragma unroll
  for (int t4 = 0; t4 < 4; ++t4) {
    float4 v = frp[t4];
    f2[t4 * 4 + 0] = v.x; f2[t4 * 4 + 1] = v.y; f2[t4 * 4 + 2] = v.z; f2[t4 * 4 + 3] = v.w;
  }
#pragma unroll
  for (int i = 0; i < 16; ++i) {
    int nn = i * 4 + q;
    float s = 0.f;
#pragma unroll
    for (int d2 = 0; d2 < 16; ++d2) {
      int d2r = (d2 + 2 * pp) & 15;
      s += f2[d2r] * w3s[pp * 16 + d2r][nn];
    }
    W23t[(size_t)(n0 + nn) * 4096 + k1] = (bf16_t)s;
  }
  float bp = 0.f;
  for (int rr = q * 32; rr < q * 32 + 32; ++rr)
    bp += b2[pb * 16 + rr] * w3s[rr][c];
  atomicAdd(&b23[n0 + c], bp);
}

// ======== split-K MFMA GEMM: 3-deep pipeline, counted vmcnt, frag-linear LDS ========
// LDS slot map (16B units): slot(row,kc) = (row>>4)*64 + kc*16 + (row&15)
// -> wave fragment read = contiguous 1KB ds_read_b128 (0 bank conflicts)
// -> staged by global_load_lds with per-lane PERMUTED global source, linear LDS dest
__global__ __launch_bounds__(256, 3)
void k_gemm3(const bf16_t* __restrict__ A,
             const bf16_t* __restrict__ Bt,
             float* __restrict__ P,
             int M, int N, int K, int ksub) {
  __shared__ bf16_t lds[3][2][4096];   // [buf][A/B][8 groups x 512 elem] = 48 KB
  const int tid = threadIdx.x, wave = tid >> 6, lane = tid & 63;
  const int m0 = blockIdx.y * 128, n0 = blockIdx.x * 128;
  const int kbase = blockIdx.z * ksub;
  const int sfr = lane & 15;        // staging: row within 16-row group
  const int skc = lane >> 4;        // staging: 8-elem k-chunk
  const int fr = lane & 15;         // fragment row/col (same decomposition)
  const int wm16 = (wave >> 1) * 4; // wave A-group base (row16)
  const int wn16 = (wave & 1) * 4;  // wave B-group base
  const int wm = wm16 * 16, wn = wn16 * 16;

  const int nkt = ksub / 32;

  auto stage = [&](int kt, int b) {
    const int k0 = kbase + kt * 32 + skc * 8;
#pragma unroll
    for (int s = 0; s < 2; ++s) {
      const int gi = wave + s * 4;
      const bf16_t* ga = A + (size_t)(m0 + gi * 16 + sfr) * K + k0;
      __builtin_amdgcn_global_load_lds(AS1(ga), AS3(&lds[b][0][gi * 512]), 16, 0, 0);
      const bf16_t* gb = Bt + (size_t)(n0 + gi * 16 + sfr) * K + k0;
      __builtin_amdgcn_global_load_lds(AS1(gb), AS3(&lds[b][1][gi * 512]), 16, 0, 0);
    }
  };

  f32x4 acc[4][4] = {};

  // prologue: tiles 0 and 1 in flight
  stage(0, 0);
  stage(1, 1);

  for (int t = 0; t < nkt; ++t) {
    // release only the oldest tile's 4 loads; keep next tile in flight (T4)
    if (t + 1 < nkt) {
      asm volatile("s_waitcnt vmcnt(4)" ::: "memory");
    } else {
      asm volatile("s_waitcnt vmcnt(0)" ::: "memory");
    }
    __builtin_amdgcn_s_barrier();
    __builtin_amdgcn_sched_barrier(0);
    if (t + 2 < nkt) stage(t + 2, (t + 2) % 3);

    const int b = t % 3;
    bf16x8 af[4], bf[4];
#pragma unroll
    for (int mi = 0; mi < 4; ++mi)
      af[mi] = *reinterpret_cast<const bf16x8*>(&lds[b][0][(wm16 + mi) * 512 + lane * 8]);
#pragma unroll
    for (int ni = 0; ni < 4; ++ni)
      bf[ni] = *reinterpret_cast<const bf16x8*>(&lds[b][1][(wn16 + ni) * 512 + lane * 8]);
    __builtin_amdgcn_s_setprio(1);
#pragma unroll
    for (int mi = 0; mi < 4; ++mi)
#pragma unroll
      for (int ni = 0; ni < 4; ++ni)
        acc[mi][ni] = __builtin_amdgcn_mfma_f32_16x16x32_bf16(af[mi], bf[ni], acc[mi][ni], 0, 0, 0);
    __builtin_amdgcn_s_setprio(0);
  }

  float* Po = P + (size_t)blockIdx.z * ((size_t)M * N);
  const int fq = lane >> 4;
#pragma unroll
  for (int mi = 0; mi < 4; ++mi)
#pragma unroll
    for (int ni = 0; ni < 4; ++ni) {
      const int col = n0 + wn + ni * 16 + fr;
#pragma unroll
      for (int j = 0; j < 4; ++j) {
        const int row = m0 + wm + mi * 16 + fq * 4 + j;
        Po[(size_t)row * N + col] = acc[mi][ni][j];
      }
    }
}

// -------- reduce split-K partials + bias -> bf16 (for out1) --------
template<int S>
__global__ __launch_bounds__(256) void k_reduce(const float* __restrict__ P, size_t sz,
                                                const float* __restrict__ bias1,
                                                bf16_t* __restrict__ out, int N) {
  const size_t i = (size_t)blockIdx.x * 256 + threadIdx.x;
  const size_t off = i * 4;
  float4 a = *(const float4*)(P + off);
#pragma unroll
  for (int s = 1; s < S; ++s) {
    float4 t = *(const float4*)(P + (size_t)s * sz + off);
    a.x += t.x; a.y += t.y; a.z += t.z; a.w += t.w;
  }
  const int col = (int)(off & (size_t)(N - 1));
  const float4 b1 = *(const float4*)(bias1 + col);
  a.x += b1.x; a.y += b1.y; a.z += b1.z; a.w += b1.w;
  bf16x4_s o{(bf16_t)a.x, (bf16_t)a.y, (bf16_t)a.z, (bf16_t)a.w};
  reinterpret_cast<bf16x4_s*>(out)[i] = o;
}

// -------- init logits = b4 --------
__global__ __launch_bounds__(256) void k_init_logits(const float* __restrict__ b4,
                                                     float* __restrict__ logits) {
  int i = blockIdx.x * 256 + threadIdx.x;
  if (i < 4096) logits[i] = b4[i & 3];
}

// -------- reduce GEMM2 partials + biases + relu, fused head partial-dot --------
template<int S>
__global__ __launch_bounds__(256) void k_reduce2_head(const float* __restrict__ P, size_t sz,
                                                      const float* __restrict__ b23,
                                                      const float* __restrict__ b3,
                                                      const float* __restrict__ w4,
                                                      float* __restrict__ logits) {
  const int bi = blockIdx.x >> 1;          // batch row
  const int half = blockIdx.x & 1;
  const int col = half * 1024 + threadIdx.x * 4;
  const size_t off = (size_t)bi * 2048 + col;
  float4 a = *(const float4*)(P + off);
#pragma unroll
  for (int s = 1; s < S; ++s) {
    float4 t = *(const float4*)(P + (size_t)s * sz + off);
    a.x += t.x; a.y += t.y; a.z += t.z; a.w += t.w;
  }
  const float4 bb1 = *(const float4*)(b23 + col);
  const float4 bb2 = *(const float4*)(b3 + col);
  float h[4];
  h[0] = fmaxf(a.x + bb1.x + bb2.x, 0.f);
  h[1] = fmaxf(a.y + bb1.y + bb2.y, 0.f);
  h[2] = fmaxf(a.z + bb1.z + bb2.z, 0.f);
  h[3] = fmaxf(a.w + bb1.w + bb2.w, 0.f);
  float s4[4] = {0.f, 0.f, 0.f, 0.f};
#pragma unroll
  for (int j = 0; j < 4; ++j) {
    const float4 w = *(const float4*)(w4 + (size_t)(col + j) * 4);
    s4[0] += h[j] * w.x; s4[1] += h[j] * w.y; s4[2] += h[j] * w.z; s4[3] += h[j] * w.w;
  }
  __shared__ float red[4][4];
  const int wave = threadIdx.x >> 6, lane = threadIdx.x & 63;
#pragma unroll
  for (int c = 0; c < 4; ++c) {
    float v = s4[c];
#pragma unroll
    for (int o = 32; o; o >>= 1) v += __shfl_down(v, o);
    if (lane == 0) red[wave][c] = v;
  }
  __syncthreads();
  if (threadIdx.x < 4) {
    float v = red[0][threadIdx.x] + red[1][threadIdx.x] + red[2][threadIdx.x] + red[3][threadIdx.x];
    atomicAdd(&logits[bi * 4 + threadIdx.x], v);
  }
}

extern "C" void kernel_launch(void* const* d_in, const int* in_sizes, int n_in,
                              void* d_out, int out_size, void* d_ws, size_t ws_size,
                              hipStream_t stream) {
  const float* data  = (const float*)d_in[0];
  const int*   comp  = (const int*)d_in[1];
  const float* fc1_w = (const float*)d_in[2];
  const float* fc1_b = (const float*)d_in[3];
  const float* fc2_w = (const float*)d_in[4];
  const float* fc2_b = (const float*)d_in[5];
  const float* w3    = (const float*)d_in[6];
  const float* b3    = (const float*)d_in[7];
  const float* w4    = (const float*)d_in[8];
  const float* b4    = (const float*)d_in[9];
  float* logits = (float*)d_out;

  char* ws = (char*)d_ws;
  const size_t MB = 1024 * 1024;
  const bool big = ws_size >= 104 * MB;   // observed: harness ws = 512 MB
  const int z1 = big ? 4 : 2;             // GEMM1 split-K
  const int z2 = big ? 8 : 4;             // GEMM2 split-K

  // layout: dataB[0,8M) Bt1[8M,40M) P[40M,40M+64M|32M)
  // phase B overlays: out1[0,8M) W23t[8M,24M) b23@24M
  bf16_t* dataB = (bf16_t*)(ws);
  bf16_t* Bt1   = (bf16_t*)(ws + 8 * MB);
  float*  P     = (float*)(ws + 40 * MB);
  bf16_t* out1  = (bf16_t*)(ws);
  bf16_t* W23t  = (bf16_t*)(ws + 8 * MB);
  float*  b23   = (float*)(ws + 24 * MB);

  // 1) data -> bf16
  k_cast_bf16<<<4096, 256, 0, stream>>>((const float4*)data, (bf16x4_s*)dataB, 1048576);
  // 2) Bt1[n][k] = bf16(fc1_w[k][n] * comp[k][n>>3])
  k_transpose<<<dim3(64, 64), 256, 0, stream>>>(fc1_w, comp, Bt1, 4096, 4096, 512);
  // 3) GEMM1: P = dataB @ Bt1^T  (M=1024 N=4096 K=4096, split z1)
  k_gemm3<<<dim3(32, 8, z1), 256, 0, stream>>>(dataB, Bt1, P, 1024, 4096, 4096, 4096 / z1);
  // 4) out1 = bf16(sum P + fc1_b)
  if (big) k_reduce<4><<<4096, 256, 0, stream>>>(P, (size_t)1024 * 4096, fc1_b, out1, 4096);
  else     k_reduce<2><<<4096, 256, 0, stream>>>(P, (size_t)1024 * 4096, fc1_b, out1, 4096);
  // 5) W23 = blockdiag(fc2_w) @ w3 folded weights; b23 = fc2_b @ w3
  hipMemsetAsync(b23, 0, 8192, stream);
  k_w23<<<dim3(32, 64), 256, 0, stream>>>(fc2_w, w3, fc2_b, W23t, b23);
  // 6) GEMM2: P = out1 @ W23t^T  (M=1024 N=2048 K=4096, split z2)
  k_gemm3<<<dim3(16, 8, z2), 256, 0, stream>>>(out1, W23t, P, 1024, 2048, 4096, 4096 / z2);
  // 7) logits = b4; then fused reduce+relu+head
  k_init_logits<<<16, 256, 0, stream>>>(b4, logits);
  if (big) k_reduce2_head<8><<<2048, 256, 0, stream>>>(P, (size_t)1024 * 2048, b23, b3, w4, logits);
  else     k_reduce2_head<4><<<2048, 256, 0, stream>>>(P, (size_t)1024 * 2048, b23, b3, w4, logits);
}